// Round 1
// baseline (238.466 us; speedup 1.0000x reference)
//
#include <hip/hip_runtime.h>

// I/O: float32 (per reference). Internal compute: bf16 MFMA (2%-relative
// threshold; measured absmax 0.0156 vs 0.0615 budget in R2/R3).
//
// R5: operand-swap epilogues. mfma(A,B) with A- and B-fragments having the
// SAME lane layout ([dim=lane&15, k=(lane>>4)*8+j]) means mfma(w_frag,
// tok_frag) computes the transposed tile: D col=lane&15 -> token, row=
// q*4+reg -> output column. Consecutive regs now map to CONTIGUOUS output
// cols, so the L3 epilogue becomes 36 global_store_dwordx4 (was 144 scalar
// dwords), L1/L2 hbuf writes become ds_write_b64 (was scalar b16), and
// biases load as float4. Also: content rows are identical across the 4
// token tiles, so L1's content half accumulates ONCE into accC[2]
// (16 MFMAs) instead of 4x-replicated (64 MFMAs); added at epilogue.
// Out stores are nontemporal (151 MB stream; keep weights resident in L2).

typedef __attribute__((ext_vector_type(4))) float  floatx4;
typedef __attribute__((ext_vector_type(8))) short  shortx8;
typedef __attribute__((ext_vector_type(4))) short  shortx4;

__device__ __forceinline__ short f2bf(float f) {
    unsigned u = __builtin_bit_cast(unsigned, f);
    u += 0x7fffu + ((u >> 16) & 1u);   // RTNE
    return (short)(u >> 16);
}

__device__ __forceinline__ shortx8 cvt8(const float* __restrict__ p) {
    floatx4 a = *(const floatx4*)p;
    floatx4 b = *(const floatx4*)(p + 4);
    shortx8 r;
    r[0] = f2bf(a[0]); r[1] = f2bf(a[1]); r[2] = f2bf(a[2]); r[3] = f2bf(a[3]);
    r[4] = f2bf(b[0]); r[5] = f2bf(b[1]); r[6] = f2bf(b[2]); r[7] = f2bf(b[3]);
    return r;
}

// Single-launch repack of W1/W2/W3 (f32 row-major [K,N]) into bf16 MFMA
// fragment order. Tile rel=(nt*KT+kt): lane l holds
// W[kt*32+(l>>4)*8+j][nt*16+(l&15)], j=0..7, 16B contiguous per lane.
// (Usable as either B-fragment [k][n] or A-fragment computing W^T.)
__global__ void repack_all(const float* __restrict__ W1,
                           const float* __restrict__ W2,
                           const float* __restrict__ W3,
                           short* __restrict__ ws) {
    int t = blockIdx.x * blockDim.x + threadIdx.x;
    int tile = t >> 6, lane = t & 63;
    const float* src; short* dst; int N, KT, rel;
    if (tile < 192)       { src = W1; dst = ws;                  N = 256;  KT = 12; rel = tile; }
    else if (tile < 448)  { src = W2; dst = ws + 98304;          N = 512;  KT = 8;  rel = tile - 192; }
    else if (tile < 1600) { src = W3; dst = ws + 98304 + 131072; N = 1152; KT = 16; rel = tile - 448; }
    else return;
    int nt = rel / KT, kt = rel - nt * KT;
    int col  = nt * 16 + (lane & 15);
    int row0 = kt * 32 + (lane >> 4) * 8;
    shortx8 v;
#pragma unroll
    for (int j = 0; j < 8; ++j) v[j] = f2bf(src[(row0 + j) * N + col]);
    *(shortx8*)(dst + rel * 512 + lane * 8) = v;
}

__global__ __launch_bounds__(512, 4) void fused_mlp(
    const float* __restrict__ content, const float* __restrict__ motion,
    const float* __restrict__ b1, const float* __restrict__ b2,
    const float* __restrict__ b3,
    const short* __restrict__ w1p, const short* __restrict__ w2p,
    const short* __restrict__ w3p, float* __restrict__ out)
{
    __shared__ short hbuf[64 * 520];   // h2 view: stride 520; h1 view: stride 264

    const int tid  = threadIdx.x;
    const int lane = tid & 63;
    const int w    = tid >> 6;        // wave 0..7: output-column-strip owner
    const int l15  = lane & 15;
    const int q    = lane >> 4;       // 0..3
    const int m0   = blockIdx.x * 64;
    const int bidx = m0 >> 9;         // batch element (512 tokens each)

    // ---------------- Layer 1: X[64,384] @ W1 -> h1[64,256] ----------------
    {
        floatx4 accC[2]    = {};      // content contribution (token-independent)
        floatx4 accM[4][2] = {};      // motion contribution per token tile
        const float* crow = content + bidx * 256;
        // content half: k = 0..255, computed ONCE (identical for all tokens)
#pragma unroll
        for (int kt = 0; kt < 8; ++kt) {
            shortx8 xb = cvt8(crow + kt * 32 + q * 8);
#pragma unroll
            for (int nt = 0; nt < 2; ++nt) {
                shortx8 wf = *(const shortx8*)(w1p + ((w * 2 + nt) * 12 + kt) * 512 + lane * 8);
                accC[nt] = __builtin_amdgcn_mfma_f32_16x16x32_bf16(wf, xb, accC[nt], 0, 0, 0);
            }
        }
        // motion half: k = 256..383
#pragma unroll
        for (int kt = 8; kt < 12; ++kt) {
            shortx8 xb[4];
#pragma unroll
            for (int tt = 0; tt < 4; ++tt)
                xb[tt] = cvt8(motion + (m0 + tt * 16 + l15) * 128 + (kt * 32 - 256) + q * 8);
#pragma unroll
            for (int nt = 0; nt < 2; ++nt) {
                shortx8 wf = *(const shortx8*)(w1p + ((w * 2 + nt) * 12 + kt) * 512 + lane * 8);
#pragma unroll
                for (int tt = 0; tt < 4; ++tt)
                    accM[tt][nt] = __builtin_amdgcn_mfma_f32_16x16x32_bf16(wf, xb[tt], accM[tt][nt], 0, 0, 0);
            }
        }
#pragma unroll
        for (int nt = 0; nt < 2; ++nt) {
            const int colb = (w * 2 + nt) * 16 + q * 4;
            const floatx4 bias = *(const floatx4*)(b1 + colb);
#pragma unroll
            for (int tt = 0; tt < 4; ++tt) {
                shortx4 pk;
#pragma unroll
                for (int r = 0; r < 4; ++r) {
                    float v = accM[tt][nt][r] + accC[nt][r] + bias[r];
                    v = (v >= 0.f) ? v : 0.2f * v;
                    pk[r] = f2bf(v);
                }
                *(shortx4*)(&hbuf[(tt * 16 + l15) * 264 + colb]) = pk;  // 8B ds_write
            }
        }
    }
    __syncthreads();

    // ---------------- Layer 2: h1[64,256] @ W2 -> h2[64,512] ----------------
    {
        floatx4 acc[4][4] = {};
#pragma unroll
        for (int kt = 0; kt < 8; ++kt) {
            shortx8 hb[4];
#pragma unroll
            for (int tt = 0; tt < 4; ++tt)
                hb[tt] = *(const shortx8*)(&hbuf[(tt * 16 + l15) * 264 + kt * 32 + q * 8]);
#pragma unroll
            for (int nt = 0; nt < 4; ++nt) {
                shortx8 wf = *(const shortx8*)(w2p + ((w * 4 + nt) * 8 + kt) * 512 + lane * 8);
#pragma unroll
                for (int tt = 0; tt < 4; ++tt)
                    acc[tt][nt] = __builtin_amdgcn_mfma_f32_16x16x32_bf16(wf, hb[tt], acc[tt][nt], 0, 0, 0);
            }
        }
        __syncthreads();   // all h1 reads complete before h2 overwrites buffer
#pragma unroll
        for (int nt = 0; nt < 4; ++nt) {
            const int colb = (w * 4 + nt) * 16 + q * 4;
            const floatx4 bias = *(const floatx4*)(b2 + colb);
#pragma unroll
            for (int tt = 0; tt < 4; ++tt) {
                shortx4 pk;
#pragma unroll
                for (int r = 0; r < 4; ++r) {
                    float v = acc[tt][nt][r] + bias[r];
                    v = (v >= 0.f) ? v : 0.2f * v;
                    pk[r] = f2bf(v);
                }
                *(shortx4*)(&hbuf[(tt * 16 + l15) * 520 + colb]) = pk;  // 8B ds_write
            }
        }
    }
    __syncthreads();

    // -------- Layer 3: h2[64,512] @ W3 -> out[64,1152], 3 passes of 48 cols --------
#pragma unroll 1
    for (int gi = 0; gi < 3; ++gi) {
        floatx4 acc[4][3] = {};   // 48 accs: keeps regs/wave <=128 -> 4 waves/SIMD
#pragma unroll 4
        for (int kt = 0; kt < 16; ++kt) {
            shortx8 hb[4];
#pragma unroll
            for (int tt = 0; tt < 4; ++tt)
                hb[tt] = *(const shortx8*)(&hbuf[(tt * 16 + l15) * 520 + kt * 32 + q * 8]);
#pragma unroll
            for (int nt = 0; nt < 3; ++nt) {
                shortx8 wf = *(const shortx8*)(w3p + ((w * 9 + gi * 3 + nt) * 16 + kt) * 512 + lane * 8);
#pragma unroll
                for (int tt = 0; tt < 4; ++tt)
                    acc[tt][nt] = __builtin_amdgcn_mfma_f32_16x16x32_bf16(wf, hb[tt], acc[tt][nt], 0, 0, 0);
            }
        }
#pragma unroll
        for (int nt = 0; nt < 3; ++nt) {
            const int colb = (w * 9 + gi * 3 + nt) * 16 + q * 4;
            const floatx4 bias = *(const floatx4*)(b3 + colb);
#pragma unroll
            for (int tt = 0; tt < 4; ++tt) {
                floatx4 v = acc[tt][nt] + bias;
                __builtin_nontemporal_store(
                    v, (floatx4*)(out + (size_t)(m0 + tt * 16 + l15) * 1152 + colb));
            }
        }
    }
}

extern "C" void kernel_launch(void* const* d_in, const int* in_sizes, int n_in,
                              void* d_out, int out_size, void* d_ws, size_t ws_size,
                              hipStream_t stream) {
    const float* content = (const float*)d_in[0];  // [64,256]
    const float* motion  = (const float*)d_in[1];  // [64,512,128]
    const float* W1 = (const float*)d_in[2];       // [384,256]
    const float* b1 = (const float*)d_in[3];
    const float* W2 = (const float*)d_in[4];       // [256,512]
    const float* b2 = (const float*)d_in[5];
    const float* W3 = (const float*)d_in[6];       // [512,1152]
    const float* b3 = (const float*)d_in[7];
    float* out = (float*)d_out;

    short* ws  = (short*)d_ws;
    short* w1p = ws;                     // 192 tiles * 512 elems
    short* w2p = ws + 98304;             // 256 tiles * 512
    short* w3p = ws + 98304 + 131072;    // 1152 tiles * 512

    repack_all<<<400, 256, 0, stream>>>(W1, W2, W3, ws);
    fused_mlp<<<512, 512, 0, stream>>>(content, motion, b1, b2, b3,
                                       w1p, w2p, w3p, out);
}